// Round 3
// baseline (283.595 us; speedup 1.0000x reference)
//
#include <hip/hip_runtime.h>
#include <cstdint>
#include <cstddef>

#define GEPS 1e-6f

using bf16x8 = __attribute__((ext_vector_type(8))) short;   // 8 bf16 = 4 VGPRs
using f32x4  = __attribute__((ext_vector_type(4))) float;   // MFMA C/D frag

__device__ inline ushort f2bf(float x) {
    union { float f; uint32_t u; } v; v.f = x;
    uint32_t r = (v.u + 0x7fffu + ((v.u >> 16) & 1u)) >> 16;  // RNE
    return (ushort)r;
}

// async global->LDS, 16 bytes per lane. LDS dest = wave-uniform base + lane*16.
__device__ inline void gll16(const void* g, void* l) {
    __builtin_amdgcn_global_load_lds(
        (const __attribute__((address_space(1))) void*)g,
        (__attribute__((address_space(3))) void*)l, 16, 0, 0);
}

// ---------------------------------------------------------------------------
// Kernel 1: pack weights to bf16, k reordered TAP-MAJOR (k = tap*256 + ci),
//   via LDS transpose so both global read and write are coalesced.
//   blocks 0..767: one conv-weight output row each
//   blocks 768..831: wo -> bf16 (4 elems/thread, vectorized)
//   blocks 832..: bias table -> [h][dy][dx] fp32
// ---------------------------------------------------------------------------
__global__ __launch_bounds__(256) void pack_k(
    const float* __restrict__ wq, const float* __restrict__ wk,
    const float* __restrict__ wv, const float* __restrict__ wo,
    const float* __restrict__ btab,
    ushort* __restrict__ Wbuf, ushort* __restrict__ wo_bf,
    float* __restrict__ bias_r)
{
    int blk = blockIdx.x, tid = threadIdx.x;
    if (blk < 768) {
        __shared__ ushort Ws[2304];
        int proj = blk >> 8, co = blk & 255;
        const float* src = ((proj == 0) ? wq : ((proj == 1) ? wk : wv)) + (size_t)co * 2304;
#pragma unroll
        for (int j = 0; j < 9; ++j) {
            int idx = j * 256 + tid;
            Ws[idx] = f2bf(src[idx]);       // coalesced fp32 read
        }
        __syncthreads();
        ushort* dst = Wbuf + (size_t)blk * 2304;
#pragma unroll
        for (int j = 0; j < 9; ++j)          // k = j*256+tid: tap=j, ci=tid
            dst[j * 256 + tid] = Ws[tid * 9 + j];   // coalesced store
        return;
    }
    if (blk < 832) {
        int t = (blk - 768) * 256 + tid;     // 0..16383, 4 elems each
        float4 v = *(const float4*)&wo[(size_t)t * 4];
        union { uint2 u; ushort s[4]; } o;
        o.s[0] = f2bf(v.x); o.s[1] = f2bf(v.y); o.s[2] = f2bf(v.z); o.s[3] = f2bf(v.w);
        *(uint2*)&wo_bf[(size_t)t * 4] = o.u;
        return;
    }
    int t = (blk - 832) * 256 + tid;
    if (t < 8 * 3969) {
        int h = t / 3969, rk = t - h * 3969;
        bias_r[t] = btab[rk * 8 + h];
    }
}

// ---------------------------------------------------------------------------
// Kernel 2: im2col via LDS transpose. Block = (b, py): one output image row.
//   Emits Ab[m][k] (k = tap*256+ci) as perfectly linear uint4 stores.
// ---------------------------------------------------------------------------
__global__ __launch_bounds__(256) void im2col_k(const float* __restrict__ x,
                                                ushort* __restrict__ Ab)
{
    __shared__ __align__(16) ushort Xs[3 * 34 * 256];   // [yy][xx+1][ci] 51 KB
    int tid = threadIdx.x;
    int blk = blockIdx.x;               // b*32 + py
    int b = blk >> 5, py = blk & 31;

#pragma unroll
    for (int yy = 0; yy < 3; ++yy) {
        Xs[(yy * 34 + 0) * 256 + tid] = 0;
        Xs[(yy * 34 + 33) * 256 + tid] = 0;
    }

#pragma unroll
    for (int it = 0; it < 24; ++it) {
        int j = it * 256 + tid;
        int ci = j / 24;
        int o = (j - ci * 24) * 4;
        int yy = o >> 5, xx = o & 31;
        int row = py - 1 + yy;
        float4 v = make_float4(0.f, 0.f, 0.f, 0.f);
        if (row >= 0 && row < 32)
            v = *(const float4*)&x[((size_t)(b * 256 + ci)) * 1024 + row * 32 + xx];
        int base = (yy * 34 + xx + 1) * 256 + ci;
        Xs[base + 0 * 256] = f2bf(v.x);
        Xs[base + 1 * 256] = f2bf(v.y);
        Xs[base + 2 * 256] = f2bf(v.z);
        Xs[base + 3 * 256] = f2bf(v.w);
    }
    __syncthreads();

    ushort* dst = Ab + (size_t)(b * 1024 + py * 32) * 2304;
#pragma unroll
    for (int it = 0; it < 36; ++it) {
        int idx = it * 256 + tid;       // 0..9215
        int ci8 = idx & 31;
        int tp = (idx >> 5) % 9;
        int px = idx / 288;
        int kh = tp / 3, kw = tp - kh * 3;
        uint4 p = *(const uint4*)&Xs[(kh * 34 + px + kw) * 256 + ci8 * 8];
        *(uint4*)&dst[(size_t)idx * 8] = p;
    }
}

// ---------------------------------------------------------------------------
// Kernel 3/6: bf16 GEMM  C[M,N] = A[M,K] * B[N,K]^T
//   64x128 tile (M x N), BK=64 -> conv grid (128,6)=768 blocks (~3/CU),
//   out-proj grid (4,64)=256. 4 waves, each 32x64 = 2x4 MFMA subtiles.
//   global_load_lds width=16 staging; XOR swizzle on the GLOBAL column so
//   LDS frag reads are 2-way aliased (free). LDS 24 KB/block.
// ---------------------------------------------------------------------------
__global__ __launch_bounds__(256, 4) void gemm_bt(
    const ushort* __restrict__ A, const ushort* __restrict__ B,
    int M, int N, int K,
    float* __restrict__ Cconv, float* __restrict__ stats,
    float* __restrict__ Cout, const float* __restrict__ bias, int mode)
{
    __shared__ __align__(16) ushort As[64 * 64];
    __shared__ __align__(16) ushort Bs[128 * 64];
    int tid = threadIdx.x;
    int mbase = blockIdx.x * 64, nbase = blockIdx.y * 128;
    int wave = tid >> 6, lane = tid & 63;
    int wm = wave & 1, wn = wave >> 1;
    int quad = lane >> 4, c = lane & 15;

    int row_s = tid >> 3;               // 0..31 staging row within chunk
    int cc8 = (tid & 7) ^ (row_s & 7);  // swizzled global column-block
    ushort* ldsA = As + wave * 512;     // wave-uniform dest base (+lane*16B)
    ushort* ldsB = Bs + wave * 512;

    f32x4 acc[2][4];
#pragma unroll
    for (int i = 0; i < 2; ++i)
#pragma unroll
        for (int j = 0; j < 4; ++j) acc[i][j] = (f32x4){0.f, 0.f, 0.f, 0.f};

    for (int kb = 0; kb < K; kb += 64) {
        __syncthreads();
#pragma unroll
        for (int R = 0; R < 2; ++R)
            gll16(A + (size_t)(mbase + R * 32 + row_s) * K + kb + cc8 * 8,
                  ldsA + R * 2048);
#pragma unroll
        for (int R = 0; R < 4; ++R)
            gll16(B + (size_t)(nbase + R * 32 + row_s) * K + kb + cc8 * 8,
                  ldsB + R * 2048);
        __syncthreads();
#pragma unroll
        for (int kq = 0; kq < 2; ++kq) {
            bf16x8 af[2], bfr[4];
            int sw = ((kq * 4 + quad) ^ (c & 7)) * 8;
#pragma unroll
            for (int i = 0; i < 2; ++i)
                af[i]  = *(const bf16x8*)&As[(wm * 32 + i * 16 + c) * 64 + sw];
#pragma unroll
            for (int j = 0; j < 4; ++j)
                bfr[j] = *(const bf16x8*)&Bs[(wn * 64 + j * 16 + c) * 64 + sw];
#pragma unroll
            for (int i = 0; i < 2; ++i)
#pragma unroll
                for (int j = 0; j < 4; ++j)
                    acc[i][j] = __builtin_amdgcn_mfma_f32_16x16x32_bf16(
                        af[i], bfr[j], acc[i][j], 0, 0, 0);
        }
    }

    if (mode == 0) {
        float s1 = 0.f, s2 = 0.f;
#pragma unroll
        for (int i = 0; i < 2; ++i) {
            int mrow = mbase + wm * 32 + i * 16 + quad * 4;
#pragma unroll
            for (int j = 0; j < 4; ++j) {
                int ncol = nbase + wn * 64 + j * 16 + c;
#pragma unroll
                for (int r = 0; r < 4; ++r) {
                    float v = acc[i][j][r];
                    Cconv[(size_t)(mrow + r) * N + ncol] = v;
                    s1 += v; s2 += v * v;
                }
            }
        }
#pragma unroll
        for (int off = 32; off > 0; off >>= 1) {
            s1 += __shfl_down(s1, off, 64);
            s2 += __shfl_down(s2, off, 64);
        }
        if (lane == 0) {
            int proj = nbase >> 8, bidx = mbase >> 10;
            atomicAdd(&stats[(proj * 8 + bidx) * 2 + 0], s1);
            atomicAdd(&stats[(proj * 8 + bidx) * 2 + 1], s2);
        }
    } else {
#pragma unroll
        for (int i = 0; i < 2; ++i) {
            int mrow0 = mbase + wm * 32 + i * 16 + quad * 4;
#pragma unroll
            for (int j = 0; j < 4; ++j) {
                int ncol = nbase + wn * 64 + j * 16 + c;
                int bb = ncol >> 10, px = ncol & 1023;
#pragma unroll
                for (int r = 0; r < 4; ++r) {
                    int o = mrow0 + r;
                    Cout[((size_t)bb * 256 + o) * 1024 + px] = acc[i][j][r] + bias[o];
                }
            }
        }
    }
}

// ---------------------------------------------------------------------------
// Kernel 4: GroupNorm(1) + exact GELU + head reshape; fp32 conv input.
// ---------------------------------------------------------------------------
__global__ void gn_k(const float* __restrict__ conv, const float* __restrict__ stats,
                     const float* __restrict__ gq, const float* __restrict__ bq,
                     const float* __restrict__ gk, const float* __restrict__ bk,
                     const float* __restrict__ gv, const float* __restrict__ bv,
                     ushort* __restrict__ qb, ushort* __restrict__ kb2,
                     ushort* __restrict__ vt)
{
    int t = blockIdx.x * 256 + threadIdx.x;     // 8192 * 96 threads
    int m = t / 96;
    int nn = (t - m * 96) * 8;
    int proj = nn >> 8, co = nn & 255;
    int b = m >> 10, px = m & 1023;
    float s1 = stats[(proj * 8 + b) * 2 + 0];
    float s2 = stats[(proj * 8 + b) * 2 + 1];
    const float Ninv = 1.f / 262144.f;
    float mu = s1 * Ninv;
    float var = fmaxf(s2 * Ninv - mu * mu, 0.f);
    float rsig = rsqrtf(var + GEPS);
    const float* gam = (proj == 0) ? gq : ((proj == 1) ? gk : gv);
    const float* bet = (proj == 0) ? bq : ((proj == 1) ? bk : bv);

    const float* src = conv + (size_t)m * 768 + nn;
    float4 in0 = *(const float4*)src;
    float4 in1 = *(const float4*)(src + 4);
    float xv[8] = {in0.x, in0.y, in0.z, in0.w, in1.x, in1.y, in1.z, in1.w};
    union { uint4 v; ushort s[8]; } outp;
#pragma unroll
    for (int e = 0; e < 8; ++e) {
        int cc = co + e;
        float xn = (xv[e] - mu) * rsig * gam[cc] + bet[cc];
        float ge = 0.5f * xn * (1.f + erff(xn * 0.70710678118654752f));
        outp.s[e] = f2bf(ge);
    }
    int h = co >> 5, d = co & 31;
    if (proj == 0) {
        *(uint4*)(qb + ((((size_t)b * 8 + h) * 1024 + px) * 32 + d)) = outp.v;
    } else if (proj == 1) {
        *(uint4*)(kb2 + ((((size_t)b * 8 + h) * 1024 + px) * 32 + d)) = outp.v;
    } else {
#pragma unroll
        for (int e = 0; e < 8; ++e)
            vt[(((size_t)b * 8 + h) * 32 + d + e) * 1024 + px] = outp.s[e];
    }
}

// ---------------------------------------------------------------------------
// Kernel 5: fused attention with relative-position bias. NO online-softmax:
//   softmax is shift-invariant and dots here are small (GN->GELU outputs,
//   |S| <~ 20), so P = exp(S) directly; l accumulated PER-LANE and reduced
//   once at the end (removes all per-iter max/alpha/reduce machinery).
// ---------------------------------------------------------------------------
__global__ __launch_bounds__(256, 2) void attn_k(
    const ushort* __restrict__ qb, const ushort* __restrict__ kb,
    const ushort* __restrict__ vt, const float* __restrict__ bias_r,
    ushort* __restrict__ attnout)
{
    __shared__ __align__(16) ushort Pl[4 * 16 * 72];
    int tid = threadIdx.x, wave = tid >> 6, lane = tid & 63;
    int quad = lane >> 4, c = lane & 15;
    int bh = blockIdx.y;               // b*8 + h
    int h = bh & 7, b = bh >> 3;
    int qbase = blockIdx.x * 64 + wave * 16;

    const ushort* Q  = qb + (size_t)bh * 1024 * 32;
    const ushort* Kp = kb + (size_t)bh * 1024 * 32;
    const ushort* Vt = vt + (size_t)bh * 32 * 1024;
    const float* brh = bias_r + h * 3969;
    ushort* Pw = Pl + wave * 16 * 72;

    bf16x8 qf = *(const bf16x8*)&Q[(qbase + c) * 32 + quad * 8];

    float l_[4] = {0.f, 0.f, 0.f, 0.f};
    f32x4 Of0 = {0.f, 0.f, 0.f, 0.f}, Of1 = {0.f, 0.f, 0.f, 0.f};
    int qy[4], qx[4];
#pragma unroll
    for (int r = 0; r < 4; ++r) {
        int qr = qbase + quad * 4 + r;
        qy[r] = qr >> 5; qx[r] = qr & 31;
    }

    for (int kb64 = 0; kb64 < 1024; kb64 += 64) {
        f32x4 S[4];
        f32x4 zf = {0.f, 0.f, 0.f, 0.f};
#pragma unroll
        for (int f = 0; f < 4; ++f) {
            bf16x8 kf = *(const bf16x8*)&Kp[(kb64 + f * 16 + c) * 32 + quad * 8];
            S[f] = __builtin_amdgcn_mfma_f32_16x16x32_bf16(qf, kf, zf, 0, 0, 0);
        }
#pragma unroll
        for (int f = 0; f < 4; ++f) {
            int key = kb64 + f * 16 + c;
            int ky = key >> 5, kx = key & 31;
#pragma unroll
            for (int r = 0; r < 4; ++r) {
                float p = __expf(S[f][r] + brh[(qy[r] - ky + 31) * 63 + (qx[r] - kx + 31)]);
                S[f][r] = p;
                l_[r] += p;
            }
        }
        // P (C-layout) -> LDS -> A-layout; per-wave slice, no barrier needed
#pragma unroll
        for (int f = 0; f < 4; ++f)
#pragma unroll
            for (int r = 0; r < 4; ++r)
                Pw[(quad * 4 + r) * 72 + f * 16 + c] = f2bf(S[f][r]);
#pragma unroll
        for (int kc = 0; kc < 2; ++kc) {
            bf16x8 pf = *(const bf16x8*)&Pw[c * 72 + kc * 32 + quad * 8];
            bf16x8 vf0 = *(const bf16x8*)&Vt[(c) * 1024 + kb64 + kc * 32 + quad * 8];
            Of0 = __builtin_amdgcn_mfma_f32_16x16x32_bf16(pf, vf0, Of0, 0, 0, 0);
            bf16x8 vf1 = *(const bf16x8*)&Vt[(16 + c) * 1024 + kb64 + kc * 32 + quad * 8];
            Of1 = __builtin_amdgcn_mfma_f32_16x16x32_bf16(pf, vf1, Of1, 0, 0, 0);
        }
    }
#pragma unroll
    for (int r = 0; r < 4; ++r) {
        float l = l_[r];
        l += __shfl_xor(l, 1, 64);
        l += __shfl_xor(l, 2, 64);
        l += __shfl_xor(l, 4, 64);
        l += __shfl_xor(l, 8, 64);
        float inv = 1.f / l;
        int qr = qbase + quad * 4 + r;
        size_t base = ((size_t)b * 1024 + qr) * 256 + h * 32;
        attnout[base + c]      = f2bf(Of0[r] * inv);
        attnout[base + 16 + c] = f2bf(Of1[r] * inv);
    }
}

// ---------------------------------------------------------------------------
extern "C" void kernel_launch(void* const* d_in, const int* in_sizes, int n_in,
                              void* d_out, int out_size, void* d_ws, size_t ws_size,
                              hipStream_t stream)
{
    const float* x    = (const float*)d_in[0];
    const float* wq   = (const float*)d_in[1];
    const float* wk   = (const float*)d_in[2];
    const float* wv   = (const float*)d_in[3];
    const float* gq   = (const float*)d_in[4];
    const float* bq   = (const float*)d_in[5];
    const float* gk   = (const float*)d_in[6];
    const float* bk   = (const float*)d_in[7];
    const float* gv   = (const float*)d_in[8];
    const float* bv   = (const float*)d_in[9];
    const float* btab = (const float*)d_in[10];
    const float* wo   = (const float*)d_in[11];
    const float* bo   = (const float*)d_in[12];
    float* out = (float*)d_out;

    char* w = (char*)d_ws;
    size_t off = 0;
    auto alloc = [&](size_t bytes) -> char* {
        char* p = w + off;
        off += (bytes + 255) & ~(size_t)255;
        return p;
    };
    ushort* Abuf    = (ushort*)alloc(8192ull * 2304 * 2);   // im2col patches
    ushort* Wbuf    = (ushort*)alloc(768ull * 2304 * 2);    // concat conv weights
    ushort* wo_bf   = (ushort*)alloc(65536ull * 2);         // out-proj weight
    float*  bias_r  = (float*)alloc(8ull * 3969 * 4);       // [h][dy][dx]
    float*  convf   = (float*)alloc(8192ull * 768 * 4);     // conv GEMM out (fp32)
    float*  stats   = (float*)alloc(256);                   // [proj][b][sum,sumsq]
    ushort* qb      = (ushort*)alloc(8ull * 8 * 1024 * 32 * 2);
    ushort* kb2     = (ushort*)alloc(8ull * 8 * 1024 * 32 * 2);
    ushort* vt      = (ushort*)alloc(8ull * 8 * 32 * 1024 * 2);
    ushort* attnout = (ushort*)alloc(8192ull * 256 * 2);

    hipMemsetAsync(stats, 0, 256, stream);
    pack_k<<<957, 256, 0, stream>>>(wq, wk, wv, wo, btab, Wbuf, wo_bf, bias_r);
    im2col_k<<<256, 256, 0, stream>>>(x, Abuf);
    gemm_bt<<<dim3(128, 6), 256, 0, stream>>>(Abuf, Wbuf, 8192, 768, 2304,
                                              convf, stats, nullptr, nullptr, 0);
    gn_k<<<3072, 256, 0, stream>>>(convf, stats, gq, bq, gk, bk, gv, bv,
                                   qb, kb2, vt);
    attn_k<<<dim3(16, 64), 256, 0, stream>>>(qb, kb2, vt, bias_r, attnout);
    gemm_bt<<<dim3(4, 64), 256, 0, stream>>>(wo_bf, attnout, 256, 8192, 256,
                                             nullptr, nullptr, out, bo, 1);
}